// Round 14
// baseline (2468.321 us; speedup 1.0000x reference)
//
#include <hip/hip_runtime.h>

// GraphSAGE encoder, restructured: aggregate AFTER linear maps; BN folded into W1.
//   N=50000, G=2000, E=800000, H=512, Z=64
// GEMM1: 256x256 tile, BK=32, 2-buffer 64KB LDS (-> 2 blocks/CU, m114 overlap),
//        __syncthreads-drain loop (gemm2-proven), conflict-free granule swizzle,
//        XCD swizzle, setprio, __launch_bounds__(512,4) caps VGPR at 128.
//        CSR-fill runs as appended blocks of the same grid (hidden in gaps).
// prep2: conv(x->bf16) + BT1(BN-folded) + BT2 + b1' + degree-count in one launch
//        (count/BT hide under conv's 605MB stream).

#define BN_EPS 1e-5f
#define GK 2000      // K of GEMM1
#define KP 2048      // padded K
#define NT1 64       // 2048/32
#define NT2 16       // 512/32

typedef __attribute__((ext_vector_type(8))) short bf16x8;
typedef __attribute__((ext_vector_type(4))) float f32x4;
typedef unsigned short u16x8 __attribute__((ext_vector_type(8)));

__device__ inline unsigned short f2bf(float f) {
    union { float f; unsigned u; } v; v.f = f;
    unsigned r = (v.u + 0x7fffu + ((v.u >> 16) & 1u)) >> 16;
    return (unsigned short)r;
}
__device__ inline float bf2f(unsigned short u) {
    union { unsigned u; float f; } v; v.u = ((unsigned)u) << 16;
    return v.f;
}

#define GLL16(gp, lp) __builtin_amdgcn_global_load_lds( \
    (const __attribute__((address_space(1))) void*)(gp), \
    (__attribute__((address_space(3))) void*)(lp), 16, 0, 0)

// ---------------- prep2: conv | BT1 (BN-folded) | BT2 | b1' | degree count ------
// blocks [0,2048): conv grid-stride; [2048,3072): BT1; [3072,3104): BT2;
// 3104: b1'; [3105,4129): count.
__global__ __launch_bounds__(256) void prep2(
    const float* __restrict__ x, unsigned short* __restrict__ xb, int N,
    const float* __restrict__ W1l, const float* __restrict__ W1r,
    const float* __restrict__ gamma, const float* __restrict__ beta,
    const float* __restrict__ mean, const float* __restrict__ var,
    const float* __restrict__ b1, unsigned short* __restrict__ BT,
    const float* __restrict__ W2l, const float* __restrict__ W2r,
    unsigned short* __restrict__ BT2, float* __restrict__ b1p,
    const int* __restrict__ ei, int* __restrict__ cnt, int E)
{
    const int bb = blockIdx.x;
    if (bb < 2048) {
        // conv: x [N][2000] f32 -> xb [N][2048] bf16 (zero-padded)
        const int total8 = N * 256;
        for (int idx = bb * 256 + threadIdx.x; idx < total8; idx += 2048 * 256) {
            int row = idx >> 8;
            int k8  = idx & 255;
            unsigned short us[8];
            if (k8 < 250) {
                const float4* p = (const float4*)(x + (size_t)row * 2000 + k8 * 8);
                float4 v0 = p[0], v1 = p[1];
                us[0]=f2bf(v0.x); us[1]=f2bf(v0.y); us[2]=f2bf(v0.z); us[3]=f2bf(v0.w);
                us[4]=f2bf(v1.x); us[5]=f2bf(v1.y); us[6]=f2bf(v1.z); us[7]=f2bf(v1.w);
            } else {
#pragma unroll
                for (int j = 0; j < 8; ++j) us[j] = 0;
            }
            *(u16x8*)&xb[(size_t)row * 2048 + k8 * 8] = *(u16x8*)us;
        }
    } else if (bb < 3072) {
        // BT1[1024][2048] = ([W1l|W1r]*diag(sc))^T, zero-padded k>=2000
        int idx = (bb - 2048) * 256 + threadIdx.x;
        int c  = idx >> 8;
        int k0 = (idx & 255) << 3;
        int cc = (c < 512) ? c : c - 512;
        float scv = gamma[cc] * rsqrtf(var[cc] + BN_EPS);
        const float* W = (c < 512) ? (W1l + cc) : (W1r + cc);
        unsigned short us[8];
#pragma unroll
        for (int j = 0; j < 8; ++j) {
            int k = k0 + j;
            float v = (k < GK) ? W[(size_t)k * 512] * scv : 0.0f;
            us[j] = f2bf(v);
        }
        *(u16x8*)&BT[(size_t)c * KP + k0] = *(u16x8*)us;
    } else if (bb < 3104) {
        // BT2[128][512] = [W2l|W2r]^T
        int idx = (bb - 3072) * 256 + threadIdx.x;
        int c  = idx >> 6;
        int k0 = (idx & 63) << 3;
        const float* W = (c < 64) ? (W2l + c) : (W2r + (c - 64));
        unsigned short us[8];
#pragma unroll
        for (int j = 0; j < 8; ++j) us[j] = f2bf(W[(size_t)(k0 + j) * 64]);
        *(u16x8*)&BT2[(size_t)c * 512 + k0] = *(u16x8*)us;
    } else if (bb == 3104) {
        // b1'[512] = b1*sc + (beta - mean*sc)
#pragma unroll
        for (int h = 0; h < 2; ++h) {
            int c = threadIdx.x + h * 256;
            float scv = gamma[c] * rsqrtf(var[c] + BN_EPS);
            b1p[c] = b1[c] * scv + (beta[c] - mean[c] * scv);
        }
    } else {
        // degree histogram (dst = ei[1][i])
        for (int i = (bb - 3105) * 256 + threadIdx.x; i < E; i += 1024 * 256)
            atomicAdd(&cnt[ei[E + i]], 1);
    }
}

// ---------------- exclusive scan over N counts (single block) ----------------
__global__ __launch_bounds__(1024) void scan_kernel(const int* __restrict__ cnt,
                                                    int* __restrict__ row_start, int n) {
    __shared__ int part[1024];
    int t = threadIdx.x;
    int chunk = (n + 1023) >> 10;
    int lo = t * chunk;
    int hi = lo + chunk; if (hi > n) hi = n;
    int s = 0;
    for (int i = lo; i < hi; ++i) s += cnt[i];
    part[t] = s;
    __syncthreads();
    for (int off = 1; off < 1024; off <<= 1) {
        int add = (t >= off) ? part[t - off] : 0;
        __syncthreads();
        part[t] += add;
        __syncthreads();
    }
    int run = (t == 0) ? 0 : part[t - 1];
    for (int i = lo; i < hi; ++i) { row_start[i] = run; run += cnt[i]; }
    if (t == 1023) row_start[n] = part[1023];
}

// ---------------- GEMM1: 256x256, BK=32, 2-buf drain loop, 2 blocks/CU ----------
// Appended blocks (b >= nwg) perform the CSR fill scatter (hidden in gaps).
__global__ __launch_bounds__(512, 4) void gemm1_256(
    const unsigned short* __restrict__ xb, int M,
    const unsigned short* __restrict__ BT,
    unsigned short* __restrict__ Y,
    const int* __restrict__ ei, int E, const int* __restrict__ row_start,
    int* __restrict__ cnt, int* __restrict__ colidx)
{
    __shared__ __align__(16) unsigned short As[2][8192];   // 256 rows x 32 k
    __shared__ __align__(16) unsigned short Bs[2][8192];   // 256 cols x 32 k

    const int t = threadIdx.x;
    const int nbr = (M + 255) >> 8;
    const int nwg = nbr * 4;
    const int b   = blockIdx.x;

    if (b >= nwg) {                         // ---- CSR fill appendage ----
        int i = (b - nwg) * 512 + t;
        if (i < E) {
            int d = ei[E + i];
            int p = atomicSub(&cnt[d], 1) - 1;
            colidx[row_start[d] + p] = ei[i];   // src
        }
        return;
    }

    const int wid = t >> 6, lane = t & 63;
    int swz = ((nwg & 7) == 0) ? (b & 7) * (nwg >> 3) + (b >> 3) : b;
    const int row0 = (swz >> 2) << 8;
    const int col0 = (swz & 3) << 8;

    // staging chunks c (16B each): c in {t, t+512}; row=c>>2, slot=c&3
    // source granule = slot ^ ((row>>1)&3) = (c&3) ^ ((c>>3)&3)  [round-7 proven]
    const int c0 = t, c1 = t + 512;
    const int g0 = ((c0 & 3) ^ ((c0 >> 3) & 3)) << 3;   // elems
    const int g1 = ((c1 & 3) ^ ((c1 >> 3) & 3)) << 3;
    int ra0 = row0 + (c0 >> 2); if (ra0 >= M) ra0 = M - 1;
    int ra1 = row0 + (c1 >> 2); if (ra1 >= M) ra1 = M - 1;
    const unsigned short* aS0 = xb + (size_t)ra0 * KP + g0;
    const unsigned short* aS1 = xb + (size_t)ra1 * KP + g1;
    const unsigned short* bS0 = BT + (size_t)(col0 + (c0 >> 2)) * KP + g0;
    const unsigned short* bS1 = BT + (size_t)(col0 + (c1 >> 2)) * KP + g1;

    const int wr = wid >> 2, wc = wid & 3;   // 2 x 4 wave grid
    const int fr16 = lane & 15;
    const int gswr = ((lane >> 4) ^ ((fr16 >> 1) & 3)) << 4;   // read byte offset

    f32x4 acc[8][4];
#pragma unroll
    for (int m = 0; m < 8; ++m)
#pragma unroll
        for (int n = 0; n < 4; ++n) acc[m][n] = (f32x4)0.0f;

#define STG(kt, buf) do {                                          \
        unsigned short* ab_ = &As[buf][0];                         \
        unsigned short* bb_ = &Bs[buf][0];                         \
        GLL16(aS0 + (size_t)(kt) * 32, ab_ + c0 * 8);              \
        GLL16(aS1 + (size_t)(kt) * 32, ab_ + c1 * 8);              \
        GLL16(bS0 + (size_t)(kt) * 32, bb_ + c0 * 8);              \
        GLL16(bS1 + (size_t)(kt) * 32, bb_ + c1 * 8);              \
    } while (0)

    STG(0, 0);
    int cur = 0;
    for (int it = 0; it < NT1; ++it) {
        __syncthreads();                 // drains vmcnt+lgkm: stage(it) landed,
                                         // prev-iter reads done by all waves
        if (it + 1 < NT1) STG(it + 1, cur ^ 1);

        const char* Ab = (const char*)&As[cur][0];
        const char* Bb = (const char*)&Bs[cur][0];
        bf16x8 af[8], bfr[4];
#pragma unroll
        for (int m = 0; m < 8; ++m)
            af[m] = *(const bf16x8*)(Ab + ((wr * 128 + m * 16 + fr16) << 6) + gswr);
#pragma unroll
        for (int n = 0; n < 4; ++n)
            bfr[n] = *(const bf16x8*)(Bb + ((wc * 64 + n * 16 + fr16) << 6) + gswr);

        __builtin_amdgcn_s_setprio(1);
#pragma unroll
        for (int m = 0; m < 8; ++m)
#pragma unroll
            for (int n = 0; n < 4; ++n)
                acc[m][n] = __builtin_amdgcn_mfma_f32_16x16x32_bf16(
                    af[m], bfr[n], acc[m][n], 0, 0, 0);
        __builtin_amdgcn_s_setprio(0);

        cur ^= 1;
    }
#undef STG

    const int crow = (lane >> 4) << 2;
#pragma unroll
    for (int m = 0; m < 8; ++m) {
        int rbase = row0 + wr * 128 + m * 16 + crow;
#pragma unroll
        for (int r = 0; r < 4; ++r) {
            int row = rbase + r;
            if (row < M) {
                unsigned short* Yp = Y + (size_t)row * 1024 + col0 + wc * 64 + fr16;
#pragma unroll
                for (int n = 0; n < 4; ++n)
                    Yp[n * 16] = f2bf(acc[m][n][r]);
            }
        }
    }
}

// ---------------- agg1: mean-gather(Yl) + b1' + self(Yr) + ReLU -> h (bf16) ------
__global__ __launch_bounds__(256) void agg1_kernel(
    const unsigned short* __restrict__ Y, unsigned short* __restrict__ Hh,
    const int* __restrict__ row_start, const int* __restrict__ colidx,
    const float* __restrict__ b1p, int n)
{
    int wid  = (blockIdx.x * blockDim.x + threadIdx.x) >> 6;
    int lane = threadIdx.x & 63;
    if (wid >= n) return;
    int c0 = lane * 8;
    float bb[8];
    *(float4*)&bb[0] = *(const float4*)&b1p[c0];
    *(float4*)&bb[4] = *(const float4*)&b1p[c0 + 4];

    int s0 = row_start[wid], s1 = row_start[wid + 1];
    float acc[8] = {0, 0, 0, 0, 0, 0, 0, 0};
    int i = s0;
    for (; i + 2 <= s1; i += 2) {
        int src0 = colidx[i], src1 = colidx[i + 1];
        u16x8 v0 = *(const u16x8*)&Y[(size_t)src0 * 1024 + c0];
        u16x8 v1 = *(const u16x8*)&Y[(size_t)src1 * 1024 + c0];
#pragma unroll
        for (int j = 0; j < 8; ++j) acc[j] += bf2f(v0[j]) + bf2f(v1[j]);
    }
    if (i < s1) {
        int src = colidx[i];
        u16x8 v = *(const u16x8*)&Y[(size_t)src * 1024 + c0];
#pragma unroll
        for (int j = 0; j < 8; ++j) acc[j] += bf2f(v[j]);
    }
    float inv = 1.0f / fmaxf((float)(s1 - s0), 1.0f);
    u16x8 sv = *(const u16x8*)&Y[(size_t)wid * 1024 + 512 + c0];
    unsigned short o[8];
#pragma unroll
    for (int j = 0; j < 8; ++j) {
        float pre = acc[j] * inv + bb[j] + bf2f(sv[j]);
        o[j] = f2bf(fmaxf(pre, 0.0f));
    }
    *(u16x8*)&Hh[(size_t)wid * 512 + c0] = *(u16x8*)o;
}

// ---------------- GEMM2: U[M x 128](bf16) = h[M x 512](bf16) @ BT2^T ------------
__global__ __launch_bounds__(256) void gemm2_bf16(
    const unsigned short* __restrict__ Hh, int M,
    const unsigned short* __restrict__ BT2,
    unsigned short* __restrict__ U)
{
    __shared__ __align__(16) unsigned short As2[2][128][32];
    __shared__ __align__(16) unsigned short Bs2[2][128][32];

    const int t    = threadIdx.x;
    const int wid  = t >> 6;
    const int lane = t & 63;
    const int row0 = blockIdx.x << 7;

    const int c_lo = wid * 64 + lane;
    const int c_hi = c_lo + 256;
    const int s_lo = ((c_lo & 3) ^ ((c_lo >> 3) & 3)) << 3;
    const int s_hi = ((c_hi & 3) ^ ((c_hi >> 3) & 3)) << 3;
    int ra = row0 + (c_lo >> 2); if (ra >= M) ra = M - 1;
    int rbw = row0 + (c_hi >> 2); if (rbw >= M) rbw = M - 1;
    const unsigned short* aSrc0 = Hh + (size_t)ra * 512 + s_lo;
    const unsigned short* aSrc1 = Hh + (size_t)rbw * 512 + s_hi;
    const unsigned short* bSrc0 = BT2 + (size_t)(c_lo >> 2) * 512 + s_lo;
    const unsigned short* bSrc1 = BT2 + (size_t)(c_hi >> 2) * 512 + s_hi;

    const int wr   = wid >> 1, wc = wid & 1;
    const int fr16 = lane & 15;
    const int gsw2 = ((lane >> 4) ^ ((fr16 >> 1) & 3)) << 4;

    f32x4 acc[4][4];
#pragma unroll
    for (int m = 0; m < 4; ++m)
#pragma unroll
        for (int n = 0; n < 4; ++n) acc[m][n] = (f32x4)0.0f;

#define STAGE2(kt, buf) do {                                                  \
        int ko = (kt) * 32;                                                   \
        GLL16(aSrc0 + ko, (unsigned short*)&As2[buf][0][0] + (size_t)c_lo * 8);  \
        GLL16(aSrc1 + ko, (unsigned short*)&As2[buf][0][0] + (size_t)c_hi * 8);  \
        GLL16(bSrc0 + ko, (unsigned short*)&Bs2[buf][0][0] + (size_t)c_lo * 8);  \
        GLL16(bSrc1 + ko, (unsigned short*)&Bs2[buf][0][0] + (size_t)c_hi * 8);  \
    } while (0)

    STAGE2(0, 0);
    int cur = 0;
    for (int it = 0; it < NT2; ++it) {
        __syncthreads();
        if (it + 1 < NT2) STAGE2(it + 1, cur ^ 1);

        const char* Ab = (const char*)&As2[cur][0][0];
        const char* Bb = (const char*)&Bs2[cur][0][0];
        bf16x8 af[4], bfr[4];
#pragma unroll
        for (int m = 0; m < 4; ++m)
            af[m] = *(const bf16x8*)(Ab + ((wr * 64 + m * 16 + fr16) << 6) + gsw2);
#pragma unroll
        for (int n = 0; n < 4; ++n)
            bfr[n] = *(const bf16x8*)(Bb + ((wc * 64 + n * 16 + fr16) << 6) + gsw2);
#pragma unroll
        for (int m = 0; m < 4; ++m)
#pragma unroll
            for (int n = 0; n < 4; ++n)
                acc[m][n] = __builtin_amdgcn_mfma_f32_16x16x32_bf16(
                    af[m], bfr[n], acc[m][n], 0, 0, 0);
        cur ^= 1;
    }
#undef STAGE2

    const int crow = (lane >> 4) << 2;
#pragma unroll
    for (int m = 0; m < 4; ++m) {
        int rbase = row0 + wr * 64 + m * 16 + crow;
#pragma unroll
        for (int r = 0; r < 4; ++r) {
            int row = rbase + r;
            if (row < M) {
                unsigned short* Up = U + (size_t)row * 128 + wc * 64 + fr16;
#pragma unroll
                for (int n = 0; n < 4; ++n)
                    Up[n * 16] = f2bf(acc[m][n][r]);
            }
        }
    }
}

// ---------------- agg2: mean-gather(Ul) + b2 + self(Ur) -> out (f32) ----------------
__global__ __launch_bounds__(256) void agg2_kernel(
    const unsigned short* __restrict__ U,
    const int* __restrict__ row_start, const int* __restrict__ colidx,
    const float* __restrict__ b2, float* __restrict__ out, int n)
{
    int wid  = (blockIdx.x * blockDim.x + threadIdx.x) >> 6;
    int lane = threadIdx.x & 63;
    if (wid >= n) return;
    int s0 = row_start[wid], s1 = row_start[wid + 1];
    float acc = 0.f;
    int i = s0;
    for (; i + 2 <= s1; i += 2) {
        int src0 = colidx[i], src1 = colidx[i + 1];
        acc += bf2f(U[(size_t)src0 * 128 + lane]) + bf2f(U[(size_t)src1 * 128 + lane]);
    }
    if (i < s1) acc += bf2f(U[(size_t)colidx[i] * 128 + lane]);
    float inv = 1.0f / fmaxf((float)(s1 - s0), 1.0f);
    float z = acc * inv + b2[lane] + bf2f(U[(size_t)wid * 128 + 64 + lane]);
    out[(size_t)wid * 64 + lane] = z;
}

extern "C" void kernel_launch(void* const* d_in, const int* in_sizes, int n_in,
                              void* d_out, int out_size, void* d_ws, size_t ws_size,
                              hipStream_t stream) {
    const float* x     = (const float*)d_in[0];
    const int*   ei    = (const int*)d_in[1];
    const float* W1l   = (const float*)d_in[2];
    const float* b1    = (const float*)d_in[3];
    const float* W1r   = (const float*)d_in[4];
    const float* gamma = (const float*)d_in[5];
    const float* beta  = (const float*)d_in[6];
    const float* mean  = (const float*)d_in[7];
    const float* var   = (const float*)d_in[8];
    const float* W2l   = (const float*)d_in[9];
    const float* b2    = (const float*)d_in[10];
    const float* W2r   = (const float*)d_in[11];
    float* out = (float*)d_out;

    const int N = in_sizes[0] / 2000;   // 50000
    const int E = in_sizes[1] / 2;      // 800000
    const int nby = (N + 127) / 128;

    // Workspace (proven 315 MB aliasing layout):
    //   xb | Y | BT | BT2 | b1p | cnt | row_start | colidx
    //   Hh aliases xb (dead after gemm1); U aliases Y (dead after agg1)
    char* ws = (char*)d_ws;
    unsigned short* xb  = (unsigned short*)ws;
    unsigned short* Y   = xb + (size_t)N * KP;
    unsigned short* BT  = Y + (size_t)N * 1024;
    unsigned short* BT2 = BT + (size_t)1024 * KP;
    float* b1p     = (float*)(BT2 + (size_t)128 * 512);
    int* cnt       = (int*)(b1p + 512);
    int* row_start = cnt + N;
    int* colidx    = row_start + N + 4;
    unsigned short* Hh = xb;   // alias: xb dead after gemm1
    unsigned short* U  = Y;    // alias: Y dead after agg1

    hipMemsetAsync(cnt, 0, (size_t)N * sizeof(int), stream);

    prep2<<<4129, 256, 0, stream>>>(
        x, xb, N, W1l, W1r, gamma, beta, mean, var, b1, BT,
        W2l, W2r, BT2, b1p, ei, cnt, E);

    scan_kernel<<<1, 1024, 0, stream>>>(cnt, row_start, N);

    int nbr = (N + 255) / 256;
    int nwg = nbr * 4;
    int fillb = (E + 511) / 512;
    gemm1_256<<<nwg + fillb, 512, 0, stream>>>(
        xb, N, BT, Y, ei, E, row_start, cnt, colidx);

    agg1_kernel<<<(N + 3) / 4, 256, 0, stream>>>(
        Y, Hh, row_start, colidx, b1p, N);
    gemm2_bf16<<<nby, 256, 0, stream>>>(Hh, N, BT2, U);
    agg2_kernel<<<(N + 3) / 4, 256, 0, stream>>>(
        U, row_start, colidx, b2, out, N);
}

// Round 15
// 681.080 us; speedup vs baseline: 3.6241x; 3.6241x over previous
//
#include <hip/hip_runtime.h>

// GraphSAGE encoder, restructured: aggregate AFTER linear maps; BN folded into W1.
//   N=50000, G=2000, E=800000, H=512, Z=64
// GEMM1: round-13 8-phase BK=64 schedule (best measured: 280.9 us, no spill).
// convfill: x->bf16 conversion (BW-bound) fused with CSR fill (latency-bound).
// prep_fused: BT1(BN-folded) + BT2 + b1' + degree-count in one launch.
// agg1/agg2: 4x edge unroll.

#define BN_EPS 1e-5f
#define GK 2000      // K of GEMM1
#define KP 2048      // padded K
#define NKT 32       // 2048/64 K-tiles of GEMM1
#define NT2 16       // 512/32

typedef __attribute__((ext_vector_type(8))) short bf16x8;
typedef __attribute__((ext_vector_type(4))) float f32x4;
typedef unsigned short u16x8 __attribute__((ext_vector_type(8)));

__device__ inline unsigned short f2bf(float f) {
    union { float f; unsigned u; } v; v.f = f;
    unsigned r = (v.u + 0x7fffu + ((v.u >> 16) & 1u)) >> 16;
    return (unsigned short)r;
}
__device__ inline float bf2f(unsigned short u) {
    union { unsigned u; float f; } v; v.u = ((unsigned)u) << 16;
    return v.f;
}

#define GLL16(gp, lp) __builtin_amdgcn_global_load_lds( \
    (const __attribute__((address_space(1))) void*)(gp), \
    (__attribute__((address_space(3))) void*)(lp), 16, 0, 0)

// ---------------- fused prep: BT1 (BN-folded) | BT2 | b1' | degree count --------
__global__ __launch_bounds__(256) void prep_fused(
    const float* __restrict__ W1l, const float* __restrict__ W1r,
    const float* __restrict__ gamma, const float* __restrict__ beta,
    const float* __restrict__ mean, const float* __restrict__ var,
    const float* __restrict__ b1, unsigned short* __restrict__ BT,
    const float* __restrict__ W2l, const float* __restrict__ W2r,
    unsigned short* __restrict__ BT2, float* __restrict__ b1p,
    const int* __restrict__ ei, int* __restrict__ cnt, int E)
{
    const int bb = blockIdx.x;
    if (bb < 1024) {
        int idx = bb * 256 + threadIdx.x;
        int c  = idx >> 8;
        int k0 = (idx & 255) << 3;
        int cc = (c < 512) ? c : c - 512;
        float scv = gamma[cc] * rsqrtf(var[cc] + BN_EPS);
        const float* W = (c < 512) ? (W1l + cc) : (W1r + cc);
        unsigned short us[8];
#pragma unroll
        for (int j = 0; j < 8; ++j) {
            int k = k0 + j;
            float v = (k < GK) ? W[(size_t)k * 512] * scv : 0.0f;
            us[j] = f2bf(v);
        }
        *(u16x8*)&BT[(size_t)c * KP + k0] = *(u16x8*)us;
    } else if (bb < 1056) {
        int idx = (bb - 1024) * 256 + threadIdx.x;
        int c  = idx >> 6;
        int k0 = (idx & 63) << 3;
        const float* W = (c < 64) ? (W2l + c) : (W2r + (c - 64));
        unsigned short us[8];
#pragma unroll
        for (int j = 0; j < 8; ++j) us[j] = f2bf(W[(size_t)(k0 + j) * 64]);
        *(u16x8*)&BT2[(size_t)c * 512 + k0] = *(u16x8*)us;
    } else if (bb == 1056) {
#pragma unroll
        for (int h = 0; h < 2; ++h) {
            int c = threadIdx.x + h * 256;
            float scv = gamma[c] * rsqrtf(var[c] + BN_EPS);
            b1p[c] = b1[c] * scv + (beta[c] - mean[c] * scv);
        }
    } else {
        for (int i = (bb - 1057) * 256 + threadIdx.x; i < E; i += 1024 * 256)
            atomicAdd(&cnt[ei[E + i]], 1);
    }
}

// ---------------- exclusive scan over N counts (single block) ----------------
__global__ __launch_bounds__(1024) void scan_kernel(const int* __restrict__ cnt,
                                                    int* __restrict__ row_start, int n) {
    __shared__ int part[1024];
    int t = threadIdx.x;
    int chunk = (n + 1023) >> 10;
    int lo = t * chunk;
    int hi = lo + chunk; if (hi > n) hi = n;
    int s = 0;
    for (int i = lo; i < hi; ++i) s += cnt[i];
    part[t] = s;
    __syncthreads();
    for (int off = 1; off < 1024; off <<= 1) {
        int add = (t >= off) ? part[t - off] : 0;
        __syncthreads();
        part[t] += add;
        __syncthreads();
    }
    int run = (t == 0) ? 0 : part[t - 1];
    for (int i = lo; i < hi; ++i) { row_start[i] = run; run += cnt[i]; }
    if (t == 1023) row_start[n] = part[1023];
}

// ---------------- conv (x f32 -> xb bf16) fused with CSR fill ----------------
__global__ __launch_bounds__(256) void convfill_kernel(
    const float* __restrict__ x, unsigned short* __restrict__ xb, int N,
    const int* __restrict__ ei, int E, const int* __restrict__ row_start,
    int* __restrict__ cnt, int* __restrict__ colidx)
{
    const int bb = blockIdx.x;
    if (bb < 2048) {
        const int total8 = N * 256;
        for (int idx = bb * 256 + threadIdx.x; idx < total8; idx += 2048 * 256) {
            int row = idx >> 8;
            int k8  = idx & 255;
            unsigned short us[8];
            if (k8 < 250) {
                const float4* p = (const float4*)(x + (size_t)row * 2000 + k8 * 8);
                float4 v0 = p[0], v1 = p[1];
                us[0]=f2bf(v0.x); us[1]=f2bf(v0.y); us[2]=f2bf(v0.z); us[3]=f2bf(v0.w);
                us[4]=f2bf(v1.x); us[5]=f2bf(v1.y); us[6]=f2bf(v1.z); us[7]=f2bf(v1.w);
            } else {
#pragma unroll
                for (int j = 0; j < 8; ++j) us[j] = 0;
            }
            *(u16x8*)&xb[(size_t)row * 2048 + k8 * 8] = *(u16x8*)us;
        }
    } else {
        int i = (bb - 2048) * 256 + threadIdx.x;
        if (i < E) {
            int d = ei[E + i];
            int p = atomicSub(&cnt[d], 1) - 1;
            colidx[row_start[d] + p] = ei[i];   // src
        }
    }
}

// ---------------- GEMM1: 256x256, BK=64, 8-phase, counted vmcnt(6) --------------
__global__ __launch_bounds__(512) void gemm1_256(
    const unsigned short* __restrict__ xb, int M,
    const unsigned short* __restrict__ BT,
    unsigned short* __restrict__ Y)
{
    __shared__ __align__(16) unsigned short As[2][16384];   // 256 rows x 64 k
    __shared__ __align__(16) unsigned short Bs[2][16384];   // 256 cols x 64 k

    const int t = threadIdx.x, wid = t >> 6, lane = t & 63;
    const int nbr = (M + 255) >> 8;
    const int nwg = nbr * 4;
    const int b   = blockIdx.x;
    int swz = ((nwg & 7) == 0) ? (b & 7) * (nwg >> 3) + (b >> 3) : b;
    const int row0 = (swz >> 2) << 8;
    const int col0 = (swz & 3) << 8;

    const unsigned short* aSrc[4];
    const unsigned short* bSrc[4];
#pragma unroll
    for (int j = 0; j < 4; ++j) {
        int c = t + 512 * j;
        int l = (c & 7) ^ ((c >> 3) & 7);
        int rA = row0 + (c >> 3); if (rA >= M) rA = M - 1;
        aSrc[j] = xb + (size_t)rA * KP + l * 8;
        bSrc[j] = BT + (size_t)(col0 + (c >> 3)) * KP + l * 8;
    }

#define STG_HA0(kt, buf) do { \
        GLL16(aSrc[0] + (size_t)(kt) * 64, &As[buf][(size_t)t * 8]); \
        GLL16(aSrc[1] + (size_t)(kt) * 64, &As[buf][(size_t)(t + 512) * 8]); } while (0)
#define STG_HA1(kt, buf) do { \
        GLL16(aSrc[2] + (size_t)(kt) * 64, &As[buf][(size_t)(1024 + t) * 8]); \
        GLL16(aSrc[3] + (size_t)(kt) * 64, &As[buf][(size_t)(1536 + t) * 8]); } while (0)
#define STG_HB0(kt, buf) do { \
        GLL16(bSrc[0] + (size_t)(kt) * 64, &Bs[buf][(size_t)t * 8]); \
        GLL16(bSrc[1] + (size_t)(kt) * 64, &Bs[buf][(size_t)(t + 512) * 8]); } while (0)
#define STG_HB1(kt, buf) do { \
        GLL16(bSrc[2] + (size_t)(kt) * 64, &Bs[buf][(size_t)(1024 + t) * 8]); \
        GLL16(bSrc[3] + (size_t)(kt) * 64, &Bs[buf][(size_t)(1536 + t) * 8]); } while (0)

    const int wr = wid >> 2, wc = wid & 3;
    const int fr16 = lane & 15;
    const int j4  = lane >> 4;
    const int sl7 = fr16 & 7;
    const int sA0 = ((j4    ) ^ sl7) << 4;
    const int sA1 = ((4 + j4) ^ sl7) << 4;
    const int rbA = (wr * 128 + fr16) << 7;
    const int rbB = (wc * 64  + fr16) << 7;

    f32x4 acc[8][4];
#pragma unroll
    for (int m = 0; m < 8; ++m)
#pragma unroll
        for (int n = 0; n < 4; ++n) acc[m][n] = (f32x4)0.0f;

    STG_HB0(0, 0); STG_HA0(0, 0); STG_HA1(0, 0); STG_HB1(0, 0);
    STG_HB0(1, 1); STG_HA0(1, 1); STG_HA1(1, 1);
    asm volatile("s_waitcnt vmcnt(6)" ::: "memory");
    __builtin_amdgcn_s_barrier();
    __builtin_amdgcn_sched_barrier(0);

    for (int tk = 0; tk < NKT; ++tk) {
        const int buf = tk & 1, obuf = buf ^ 1;
        const char* Ab = (const char*)&As[buf][0];
        const char* Bb = (const char*)&Bs[buf][0];
        bf16x8 af[4][2], bfA[2][2], bfB[2][2];

        // ---- phase 1 ----
#pragma unroll
        for (int m = 0; m < 4; ++m) {
            af[m][0] = *(const bf16x8*)(Ab + rbA + (m << 11) + sA0);
            af[m][1] = *(const bf16x8*)(Ab + rbA + (m << 11) + sA1);
        }
#pragma unroll
        for (int n = 0; n < 2; ++n) {
            bfA[n][0] = *(const bf16x8*)(Bb + rbB + (n << 11) + sA0);
            bfA[n][1] = *(const bf16x8*)(Bb + rbB + (n << 11) + sA1);
        }
        STG_HB1(tk + 1, obuf);
        __builtin_amdgcn_s_barrier();
        __builtin_amdgcn_sched_barrier(0);
        __builtin_amdgcn_s_setprio(1);
#pragma unroll
        for (int m = 0; m < 4; ++m)
#pragma unroll
            for (int n = 0; n < 2; ++n) {
                acc[m][n] = __builtin_amdgcn_mfma_f32_16x16x32_bf16(
                    af[m][0], bfA[n][0], acc[m][n], 0, 0, 0);
                acc[m][n] = __builtin_amdgcn_mfma_f32_16x16x32_bf16(
                    af[m][1], bfA[n][1], acc[m][n], 0, 0, 0);
            }
        __builtin_amdgcn_s_setprio(0);

        // ---- phase 2 ----
#pragma unroll
        for (int n = 0; n < 2; ++n) {
            bfB[n][0] = *(const bf16x8*)(Bb + rbB + ((n + 2) << 11) + sA0);
            bfB[n][1] = *(const bf16x8*)(Bb + rbB + ((n + 2) << 11) + sA1);
        }
        asm volatile("s_waitcnt lgkmcnt(0)" ::: "memory");
        __builtin_amdgcn_s_barrier();
        __builtin_amdgcn_sched_barrier(0);
        __builtin_amdgcn_s_setprio(1);
#pragma unroll
        for (int m = 0; m < 4; ++m)
#pragma unroll
            for (int n = 0; n < 2; ++n) {
                acc[m][n + 2] = __builtin_amdgcn_mfma_f32_16x16x32_bf16(
                    af[m][0], bfB[n][0], acc[m][n + 2], 0, 0, 0);
                acc[m][n + 2] = __builtin_amdgcn_mfma_f32_16x16x32_bf16(
                    af[m][1], bfB[n][1], acc[m][n + 2], 0, 0, 0);
            }
        __builtin_amdgcn_s_setprio(0);

        // ---- phase 3 ----
#pragma unroll
        for (int m = 0; m < 4; ++m) {
            af[m][0] = *(const bf16x8*)(Ab + rbA + ((m + 4) << 11) + sA0);
            af[m][1] = *(const bf16x8*)(Ab + rbA + ((m + 4) << 11) + sA1);
        }
        STG_HB0(tk + 2, buf);
        asm volatile("s_waitcnt lgkmcnt(0)" ::: "memory");
        __builtin_amdgcn_s_barrier();
        __builtin_amdgcn_sched_barrier(0);
        __builtin_amdgcn_s_setprio(1);
#pragma unroll
        for (int m = 0; m < 4; ++m)
#pragma unroll
            for (int n = 0; n < 2; ++n) {
                acc[m + 4][n] = __builtin_amdgcn_mfma_f32_16x16x32_bf16(
                    af[m][0], bfA[n][0], acc[m + 4][n], 0, 0, 0);
                acc[m + 4][n] = __builtin_amdgcn_mfma_f32_16x16x32_bf16(
                    af[m][1], bfA[n][1], acc[m + 4][n], 0, 0, 0);
            }
        __builtin_amdgcn_s_setprio(0);

        // ---- phase 4 ----
        STG_HA0(tk + 2, buf);
        STG_HA1(tk + 2, buf);
        asm volatile("s_waitcnt vmcnt(6)" ::: "memory");
        __builtin_amdgcn_s_barrier();
        __builtin_amdgcn_sched_barrier(0);
        __builtin_amdgcn_s_setprio(1);
#pragma unroll
        for (int m = 0; m < 4; ++m)
#pragma unroll
            for (int n = 0; n < 2; ++n) {
                acc[m + 4][n + 2] = __builtin_amdgcn_mfma_f32_16x16x32_bf16(
                    af[m][0], bfB[n][0], acc[m + 4][n + 2], 0, 0, 0);
                acc[m + 4][n + 2] = __builtin_amdgcn_mfma_f32_16x16x32_bf16(
                    af[m][1], bfB[n][1], acc[m + 4][n + 2], 0, 0, 0);
            }
        __builtin_amdgcn_s_setprio(0);
    }
#undef STG_HA0
#undef STG_HA1
#undef STG_HB0
#undef STG_HB1

    const int crow = (lane >> 4) << 2;
#pragma unroll
    for (int m = 0; m < 8; ++m) {
        int rbase = row0 + wr * 128 + m * 16 + crow;
#pragma unroll
        for (int r = 0; r < 4; ++r) {
            int row = rbase + r;
            if (row < M) {
                unsigned short* Yp = Y + (size_t)row * 1024 + col0 + wc * 64 + fr16;
#pragma unroll
                for (int n = 0; n < 4; ++n)
                    Yp[n * 16] = f2bf(acc[m][n][r]);
            }
        }
    }
}

// ---------------- agg1: mean-gather(Yl) + b1' + self(Yr) + ReLU -> h (bf16) ------
__global__ __launch_bounds__(256) void agg1_kernel(
    const unsigned short* __restrict__ Y, unsigned short* __restrict__ Hh,
    const int* __restrict__ row_start, const int* __restrict__ colidx,
    const float* __restrict__ b1p, int n)
{
    int wid  = (blockIdx.x * blockDim.x + threadIdx.x) >> 6;
    int lane = threadIdx.x & 63;
    if (wid >= n) return;
    int c0 = lane * 8;
    float bb[8];
    *(float4*)&bb[0] = *(const float4*)&b1p[c0];
    *(float4*)&bb[4] = *(const float4*)&b1p[c0 + 4];

    int s0 = row_start[wid], s1 = row_start[wid + 1];
    float acc[8] = {0, 0, 0, 0, 0, 0, 0, 0};
    int i = s0;
    for (; i + 4 <= s1; i += 4) {
        int src0 = colidx[i], src1 = colidx[i + 1];
        int src2 = colidx[i + 2], src3 = colidx[i + 3];
        u16x8 v0 = *(const u16x8*)&Y[(size_t)src0 * 1024 + c0];
        u16x8 v1 = *(const u16x8*)&Y[(size_t)src1 * 1024 + c0];
        u16x8 v2 = *(const u16x8*)&Y[(size_t)src2 * 1024 + c0];
        u16x8 v3 = *(const u16x8*)&Y[(size_t)src3 * 1024 + c0];
#pragma unroll
        for (int j = 0; j < 8; ++j)
            acc[j] += (bf2f(v0[j]) + bf2f(v1[j])) + (bf2f(v2[j]) + bf2f(v3[j]));
    }
    for (; i < s1; ++i) {
        int src = colidx[i];
        u16x8 v = *(const u16x8*)&Y[(size_t)src * 1024 + c0];
#pragma unroll
        for (int j = 0; j < 8; ++j) acc[j] += bf2f(v[j]);
    }
    float inv = 1.0f / fmaxf((float)(s1 - s0), 1.0f);
    u16x8 sv = *(const u16x8*)&Y[(size_t)wid * 1024 + 512 + c0];
    unsigned short o[8];
#pragma unroll
    for (int j = 0; j < 8; ++j) {
        float pre = acc[j] * inv + bb[j] + bf2f(sv[j]);
        o[j] = f2bf(fmaxf(pre, 0.0f));
    }
    *(u16x8*)&Hh[(size_t)wid * 512 + c0] = *(u16x8*)o;
}

// ---------------- GEMM2: U[M x 128](bf16) = h[M x 512](bf16) @ BT2^T ------------
__global__ __launch_bounds__(256) void gemm2_bf16(
    const unsigned short* __restrict__ Hh, int M,
    const unsigned short* __restrict__ BT2,
    unsigned short* __restrict__ U)
{
    __shared__ __align__(16) unsigned short As2[2][128][32];
    __shared__ __align__(16) unsigned short Bs2[2][128][32];

    const int t    = threadIdx.x;
    const int wid  = t >> 6;
    const int lane = t & 63;
    const int row0 = blockIdx.x << 7;

    const int c_lo = wid * 64 + lane;
    const int c_hi = c_lo + 256;
    const int s_lo = ((c_lo & 3) ^ ((c_lo >> 3) & 3)) << 3;
    const int s_hi = ((c_hi & 3) ^ ((c_hi >> 3) & 3)) << 3;
    int ra = row0 + (c_lo >> 2); if (ra >= M) ra = M - 1;
    int rbw = row0 + (c_hi >> 2); if (rbw >= M) rbw = M - 1;
    const unsigned short* aSrc0 = Hh + (size_t)ra * 512 + s_lo;
    const unsigned short* aSrc1 = Hh + (size_t)rbw * 512 + s_hi;
    const unsigned short* bSrc0 = BT2 + (size_t)(c_lo >> 2) * 512 + s_lo;
    const unsigned short* bSrc1 = BT2 + (size_t)(c_hi >> 2) * 512 + s_hi;

    const int wr   = wid >> 1, wc = wid & 1;
    const int fr16 = lane & 15;
    const int gsw2 = ((lane >> 4) ^ ((fr16 >> 1) & 3)) << 4;

    f32x4 acc[4][4];
#pragma unroll
    for (int m = 0; m < 4; ++m)
#pragma unroll
        for (int n = 0; n < 4; ++n) acc[m][n] = (f32x4)0.0f;

#define STAGE2(kt, buf) do {                                                  \
        int ko = (kt) * 32;                                                   \
        GLL16(aSrc0 + ko, (unsigned short*)&As2[buf][0][0] + (size_t)c_lo * 8);  \
        GLL16(aSrc1 + ko, (unsigned short*)&As2[buf][0][0] + (size_t)c_hi * 8);  \
        GLL16(bSrc0 + ko, (unsigned short*)&Bs2[buf][0][0] + (size_t)c_lo * 8);  \
        GLL16(bSrc1 + ko, (unsigned short*)&Bs2[buf][0][0] + (size_t)c_hi * 8);  \
    } while (0)

    STAGE2(0, 0);
    int cur = 0;
    for (int it = 0; it < NT2; ++it) {
        __syncthreads();
        if (it + 1 < NT2) STAGE2(it + 1, cur ^ 1);

        const char* Ab = (const char*)&As2[cur][0][0];
        const char* Bb = (const char*)&Bs2[cur][0][0];
        bf16x8 af[4], bfr[4];
#pragma unroll
        for (int m = 0; m < 4; ++m)
            af[m] = *(const bf16x8*)(Ab + ((wr * 64 + m * 16 + fr16) << 6) + gsw2);
#pragma unroll
        for (int n = 0; n < 4; ++n)
            bfr[n] = *(const bf16x8*)(Bb + ((wc * 64 + n * 16 + fr16) << 6) + gsw2);
#pragma unroll
        for (int m = 0; m < 4; ++m)
#pragma unroll
            for (int n = 0; n < 4; ++n)
                acc[m][n] = __builtin_amdgcn_mfma_f32_16x16x32_bf16(
                    af[m], bfr[n], acc[m][n], 0, 0, 0);
        cur ^= 1;
    }
#undef STAGE2

    const int crow = (lane >> 4) << 2;
#pragma unroll
    for (int m = 0; m < 4; ++m) {
        int rbase = row0 + wr * 64 + m * 16 + crow;
#pragma unroll
        for (int r = 0; r < 4; ++r) {
            int row = rbase + r;
            if (row < M) {
                unsigned short* Up = U + (size_t)row * 128 + wc * 64 + fr16;
#pragma unroll
                for (int n = 0; n < 4; ++n)
                    Up[n * 16] = f2bf(acc[m][n][r]);
            }
        }
    }
}

// ---------------- agg2: mean-gather(Ul) + b2 + self(Ur) -> out (f32) ----------------
__global__ __launch_bounds__(256) void agg2_kernel(
    const unsigned short* __restrict__ U,
    const int* __restrict__ row_start, const int* __restrict__ colidx,
    const float* __restrict__ b2, float* __restrict__ out, int n)
{
    int wid  = (blockIdx.x * blockDim.x + threadIdx.x) >> 6;
    int lane = threadIdx.x & 63;
    if (wid >= n) return;
    int s0 = row_start[wid], s1 = row_start[wid + 1];
    float acc = 0.f;
    int i = s0;
    for (; i + 4 <= s1; i += 4) {
        int src0 = colidx[i], src1 = colidx[i + 1];
        int src2 = colidx[i + 2], src3 = colidx[i + 3];
        acc += (bf2f(U[(size_t)src0 * 128 + lane]) + bf2f(U[(size_t)src1 * 128 + lane]))
             + (bf2f(U[(size_t)src2 * 128 + lane]) + bf2f(U[(size_t)src3 * 128 + lane]));
    }
    for (; i < s1; ++i) acc += bf2f(U[(size_t)colidx[i] * 128 + lane]);
    float inv = 1.0f / fmaxf((float)(s1 - s0), 1.0f);
    float z = acc * inv + b2[lane] + bf2f(U[(size_t)wid * 128 + 64 + lane]);
    out[(size_t)wid * 64 + lane] = z;
}

extern "C" void kernel_launch(void* const* d_in, const int* in_sizes, int n_in,
                              void* d_out, int out_size, void* d_ws, size_t ws_size,
                              hipStream_t stream) {
    const float* x     = (const float*)d_in[0];
    const int*   ei    = (const int*)d_in[1];
    const float* W1l   = (const float*)d_in[2];
    const float* b1    = (const float*)d_in[3];
    const float* W1r   = (const float*)d_in[4];
    const float* gamma = (const float*)d_in[5];
    const float* beta  = (const float*)d_in[6];
    const float* mean  = (const float*)d_in[7];
    const float* var   = (const float*)d_in[8];
    const float* W2l   = (const float*)d_in[9];
    const float* b2    = (const float*)d_in[10];
    const float* W2r   = (const float*)d_in[11];
    float* out = (float*)d_out;

    const int N = in_sizes[0] / 2000;   // 50000
    const int E = in_sizes[1] / 2;      // 800000
    const int nby = (N + 127) / 128;

    // Workspace (proven 315 MB aliasing layout):
    //   xb | Y | BT | BT2 | b1p | cnt | row_start | colidx
    //   Hh aliases xb (dead after gemm1); U aliases Y (dead after agg1)
    char* ws = (char*)d_ws;
    unsigned short* xb  = (unsigned short*)ws;
    unsigned short* Y   = xb + (size_t)N * KP;
    unsigned short* BT  = Y + (size_t)N * 1024;
    unsigned short* BT2 = BT + (size_t)1024 * KP;
    float* b1p     = (float*)(BT2 + (size_t)128 * 512);
    int* cnt       = (int*)(b1p + 512);
    int* row_start = cnt + N;
    int* colidx    = row_start + N + 4;
    unsigned short* Hh = xb;   // alias: xb dead after gemm1
    unsigned short* U  = Y;    // alias: Y dead after agg1

    hipMemsetAsync(cnt, 0, (size_t)N * sizeof(int), stream);

    prep_fused<<<2081, 256, 0, stream>>>(
        W1l, W1r, gamma, beta, mean, var, b1, BT, W2l, W2r, BT2, b1p,
        ei, cnt, E);

    scan_kernel<<<1, 1024, 0, stream>>>(cnt, row_start, N);

    int eb = (E + 255) / 256;
    convfill_kernel<<<2048 + eb, 256, 0, stream>>>(
        x, xb, N, ei, E, row_start, cnt, colidx);

    int nbr = (N + 255) / 256;
    gemm1_256<<<nbr * 4, 512, 0, stream>>>(xb, N, BT, Y);
    agg1_kernel<<<(N + 3) / 4, 256, 0, stream>>>(
        Y, Hh, row_start, colidx, b1p, N);
    gemm2_bf16<<<nby, 256, 0, stream>>>(Hh, N, BT2, U);
    agg2_kernel<<<(N + 3) / 4, 256, 0, stream>>>(
        U, row_start, colidx, b2, out, N);
}

// Round 16
// 653.894 us; speedup vs baseline: 3.7748x; 1.0416x over previous
//
#include <hip/hip_runtime.h>

// GraphSAGE encoder, restructured: aggregate AFTER linear maps; BN folded into W1.
//   N=50000, G=2000, E=800000, H=512, Z=64
// GEMM1: round-13/15 8-phase BK=64 schedule (280 us, proven); CSR-fill runs as
//        appended blocks of the same grid (round-14-proven trick, hidden).
// prep2: conv(x->bf16) + BT1(BN-folded) + BT2 + b1' + degree-count in one launch
//        (BT/count hide under conv's 605MB stream; round-14-proven).
// agg1/agg2: 4x edge unroll.

#define BN_EPS 1e-5f
#define GK 2000      // K of GEMM1
#define KP 2048      // padded K
#define NKT 32       // 2048/64 K-tiles of GEMM1
#define NT2 16       // 512/32

typedef __attribute__((ext_vector_type(8))) short bf16x8;
typedef __attribute__((ext_vector_type(4))) float f32x4;
typedef unsigned short u16x8 __attribute__((ext_vector_type(8)));

__device__ inline unsigned short f2bf(float f) {
    union { float f; unsigned u; } v; v.f = f;
    unsigned r = (v.u + 0x7fffu + ((v.u >> 16) & 1u)) >> 16;
    return (unsigned short)r;
}
__device__ inline float bf2f(unsigned short u) {
    union { unsigned u; float f; } v; v.u = ((unsigned)u) << 16;
    return v.f;
}

#define GLL16(gp, lp) __builtin_amdgcn_global_load_lds( \
    (const __attribute__((address_space(1))) void*)(gp), \
    (__attribute__((address_space(3))) void*)(lp), 16, 0, 0)

// ---------------- prep2: conv | BT1 (BN-folded) | BT2 | b1' | degree count ------
// blocks [0,2048): conv grid-stride; [2048,3072): BT1; [3072,3104): BT2;
// 3104: b1'; [3105,4129): count.
__global__ __launch_bounds__(256) void prep2(
    const float* __restrict__ x, unsigned short* __restrict__ xb, int N,
    const float* __restrict__ W1l, const float* __restrict__ W1r,
    const float* __restrict__ gamma, const float* __restrict__ beta,
    const float* __restrict__ mean, const float* __restrict__ var,
    const float* __restrict__ b1, unsigned short* __restrict__ BT,
    const float* __restrict__ W2l, const float* __restrict__ W2r,
    unsigned short* __restrict__ BT2, float* __restrict__ b1p,
    const int* __restrict__ ei, int* __restrict__ cnt, int E)
{
    const int bb = blockIdx.x;
    if (bb < 2048) {
        // conv: x [N][2000] f32 -> xb [N][2048] bf16 (zero-padded)
        const int total8 = N * 256;
        for (int idx = bb * 256 + threadIdx.x; idx < total8; idx += 2048 * 256) {
            int row = idx >> 8;
            int k8  = idx & 255;
            unsigned short us[8];
            if (k8 < 250) {
                const float4* p = (const float4*)(x + (size_t)row * 2000 + k8 * 8);
                float4 v0 = p[0], v1 = p[1];
                us[0]=f2bf(v0.x); us[1]=f2bf(v0.y); us[2]=f2bf(v0.z); us[3]=f2bf(v0.w);
                us[4]=f2bf(v1.x); us[5]=f2bf(v1.y); us[6]=f2bf(v1.z); us[7]=f2bf(v1.w);
            } else {
#pragma unroll
                for (int j = 0; j < 8; ++j) us[j] = 0;
            }
            *(u16x8*)&xb[(size_t)row * 2048 + k8 * 8] = *(u16x8*)us;
        }
    } else if (bb < 3072) {
        // BT1[1024][2048] = ([W1l|W1r]*diag(sc))^T, zero-padded k>=2000
        int idx = (bb - 2048) * 256 + threadIdx.x;
        int c  = idx >> 8;
        int k0 = (idx & 255) << 3;
        int cc = (c < 512) ? c : c - 512;
        float scv = gamma[cc] * rsqrtf(var[cc] + BN_EPS);
        const float* W = (c < 512) ? (W1l + cc) : (W1r + cc);
        unsigned short us[8];
#pragma unroll
        for (int j = 0; j < 8; ++j) {
            int k = k0 + j;
            float v = (k < GK) ? W[(size_t)k * 512] * scv : 0.0f;
            us[j] = f2bf(v);
        }
        *(u16x8*)&BT[(size_t)c * KP + k0] = *(u16x8*)us;
    } else if (bb < 3104) {
        // BT2[128][512] = [W2l|W2r]^T
        int idx = (bb - 3072) * 256 + threadIdx.x;
        int c  = idx >> 6;
        int k0 = (idx & 63) << 3;
        const float* W = (c < 64) ? (W2l + c) : (W2r + (c - 64));
        unsigned short us[8];
#pragma unroll
        for (int j = 0; j < 8; ++j) us[j] = f2bf(W[(size_t)(k0 + j) * 64]);
        *(u16x8*)&BT2[(size_t)c * 512 + k0] = *(u16x8*)us;
    } else if (bb == 3104) {
        // b1'[512] = b1*sc + (beta - mean*sc)
#pragma unroll
        for (int h = 0; h < 2; ++h) {
            int c = threadIdx.x + h * 256;
            float scv = gamma[c] * rsqrtf(var[c] + BN_EPS);
            b1p[c] = b1[c] * scv + (beta[c] - mean[c] * scv);
        }
    } else {
        // degree histogram (dst = ei[1][i])
        for (int i = (bb - 3105) * 256 + threadIdx.x; i < E; i += 1024 * 256)
            atomicAdd(&cnt[ei[E + i]], 1);
    }
}

// ---------------- exclusive scan over N counts (single block) ----------------
__global__ __launch_bounds__(1024) void scan_kernel(const int* __restrict__ cnt,
                                                    int* __restrict__ row_start, int n) {
    __shared__ int part[1024];
    int t = threadIdx.x;
    int chunk = (n + 1023) >> 10;
    int lo = t * chunk;
    int hi = lo + chunk; if (hi > n) hi = n;
    int s = 0;
    for (int i = lo; i < hi; ++i) s += cnt[i];
    part[t] = s;
    __syncthreads();
    for (int off = 1; off < 1024; off <<= 1) {
        int add = (t >= off) ? part[t - off] : 0;
        __syncthreads();
        part[t] += add;
        __syncthreads();
    }
    int run = (t == 0) ? 0 : part[t - 1];
    for (int i = lo; i < hi; ++i) { row_start[i] = run; run += cnt[i]; }
    if (t == 1023) row_start[n] = part[1023];
}

// ---------------- GEMM1: 256x256, BK=64, 8-phase, counted vmcnt(6) --------------
// Appended blocks (b >= nwg) perform the CSR fill scatter (hidden in gaps;
// they early-exit before any barrier/LDS use).
__global__ __launch_bounds__(512) void gemm1_256(
    const unsigned short* __restrict__ xb, int M,
    const unsigned short* __restrict__ BT,
    unsigned short* __restrict__ Y,
    const int* __restrict__ ei, int E, const int* __restrict__ row_start,
    int* __restrict__ cnt, int* __restrict__ colidx)
{
    __shared__ __align__(16) unsigned short As[2][16384];   // 256 rows x 64 k
    __shared__ __align__(16) unsigned short Bs[2][16384];   // 256 cols x 64 k

    const int t = threadIdx.x;
    const int nbr = (M + 255) >> 8;
    const int nwg = nbr * 4;
    const int b   = blockIdx.x;

    if (b >= nwg) {                         // ---- CSR fill appendage ----
        int i = (b - nwg) * 512 + t;
        if (i < E) {
            int d = ei[E + i];
            int p = atomicSub(&cnt[d], 1) - 1;
            colidx[row_start[d] + p] = ei[i];   // src
        }
        return;
    }

    const int wid = t >> 6, lane = t & 63;
    int swz = ((nwg & 7) == 0) ? (b & 7) * (nwg >> 3) + (b >> 3) : b;
    const int row0 = (swz >> 2) << 8;
    const int col0 = (swz & 3) << 8;

    const unsigned short* aSrc[4];
    const unsigned short* bSrc[4];
#pragma unroll
    for (int j = 0; j < 4; ++j) {
        int c = t + 512 * j;
        int l = (c & 7) ^ ((c >> 3) & 7);
        int rA = row0 + (c >> 3); if (rA >= M) rA = M - 1;
        aSrc[j] = xb + (size_t)rA * KP + l * 8;
        bSrc[j] = BT + (size_t)(col0 + (c >> 3)) * KP + l * 8;
    }

#define STG_HA0(kt, buf) do { \
        GLL16(aSrc[0] + (size_t)(kt) * 64, &As[buf][(size_t)t * 8]); \
        GLL16(aSrc[1] + (size_t)(kt) * 64, &As[buf][(size_t)(t + 512) * 8]); } while (0)
#define STG_HA1(kt, buf) do { \
        GLL16(aSrc[2] + (size_t)(kt) * 64, &As[buf][(size_t)(1024 + t) * 8]); \
        GLL16(aSrc[3] + (size_t)(kt) * 64, &As[buf][(size_t)(1536 + t) * 8]); } while (0)
#define STG_HB0(kt, buf) do { \
        GLL16(bSrc[0] + (size_t)(kt) * 64, &Bs[buf][(size_t)t * 8]); \
        GLL16(bSrc[1] + (size_t)(kt) * 64, &Bs[buf][(size_t)(t + 512) * 8]); } while (0)
#define STG_HB1(kt, buf) do { \
        GLL16(bSrc[2] + (size_t)(kt) * 64, &Bs[buf][(size_t)(1024 + t) * 8]); \
        GLL16(bSrc[3] + (size_t)(kt) * 64, &Bs[buf][(size_t)(1536 + t) * 8]); } while (0)

    const int wr = wid >> 2, wc = wid & 3;
    const int fr16 = lane & 15;
    const int j4  = lane >> 4;
    const int sl7 = fr16 & 7;
    const int sA0 = ((j4    ) ^ sl7) << 4;
    const int sA1 = ((4 + j4) ^ sl7) << 4;
    const int rbA = (wr * 128 + fr16) << 7;
    const int rbB = (wc * 64  + fr16) << 7;

    f32x4 acc[8][4];
#pragma unroll
    for (int m = 0; m < 8; ++m)
#pragma unroll
        for (int n = 0; n < 4; ++n) acc[m][n] = (f32x4)0.0f;

    STG_HB0(0, 0); STG_HA0(0, 0); STG_HA1(0, 0); STG_HB1(0, 0);
    STG_HB0(1, 1); STG_HA0(1, 1); STG_HA1(1, 1);
    asm volatile("s_waitcnt vmcnt(6)" ::: "memory");
    __builtin_amdgcn_s_barrier();
    __builtin_amdgcn_sched_barrier(0);

    for (int tk = 0; tk < NKT; ++tk) {
        const int buf = tk & 1, obuf = buf ^ 1;
        const char* Ab = (const char*)&As[buf][0];
        const char* Bb = (const char*)&Bs[buf][0];
        bf16x8 af[4][2], bfA[2][2], bfB[2][2];

        // ---- phase 1 ----
#pragma unroll
        for (int m = 0; m < 4; ++m) {
            af[m][0] = *(const bf16x8*)(Ab + rbA + (m << 11) + sA0);
            af[m][1] = *(const bf16x8*)(Ab + rbA + (m << 11) + sA1);
        }
#pragma unroll
        for (int n = 0; n < 2; ++n) {
            bfA[n][0] = *(const bf16x8*)(Bb + rbB + (n << 11) + sA0);
            bfA[n][1] = *(const bf16x8*)(Bb + rbB + (n << 11) + sA1);
        }
        STG_HB1(tk + 1, obuf);
        __builtin_amdgcn_s_barrier();
        __builtin_amdgcn_sched_barrier(0);
        __builtin_amdgcn_s_setprio(1);
#pragma unroll
        for (int m = 0; m < 4; ++m)
#pragma unroll
            for (int n = 0; n < 2; ++n) {
                acc[m][n] = __builtin_amdgcn_mfma_f32_16x16x32_bf16(
                    af[m][0], bfA[n][0], acc[m][n], 0, 0, 0);
                acc[m][n] = __builtin_amdgcn_mfma_f32_16x16x32_bf16(
                    af[m][1], bfA[n][1], acc[m][n], 0, 0, 0);
            }
        __builtin_amdgcn_s_setprio(0);

        // ---- phase 2 ----
#pragma unroll
        for (int n = 0; n < 2; ++n) {
            bfB[n][0] = *(const bf16x8*)(Bb + rbB + ((n + 2) << 11) + sA0);
            bfB[n][1] = *(const bf16x8*)(Bb + rbB + ((n + 2) << 11) + sA1);
        }
        asm volatile("s_waitcnt lgkmcnt(0)" ::: "memory");
        __builtin_amdgcn_s_barrier();
        __builtin_amdgcn_sched_barrier(0);
        __builtin_amdgcn_s_setprio(1);
#pragma unroll
        for (int m = 0; m < 4; ++m)
#pragma unroll
            for (int n = 0; n < 2; ++n) {
                acc[m][n + 2] = __builtin_amdgcn_mfma_f32_16x16x32_bf16(
                    af[m][0], bfB[n][0], acc[m][n + 2], 0, 0, 0);
                acc[m][n + 2] = __builtin_amdgcn_mfma_f32_16x16x32_bf16(
                    af[m][1], bfB[n][1], acc[m][n + 2], 0, 0, 0);
            }
        __builtin_amdgcn_s_setprio(0);

        // ---- phase 3 ----
#pragma unroll
        for (int m = 0; m < 4; ++m) {
            af[m][0] = *(const bf16x8*)(Ab + rbA + ((m + 4) << 11) + sA0);
            af[m][1] = *(const bf16x8*)(Ab + rbA + ((m + 4) << 11) + sA1);
        }
        STG_HB0(tk + 2, buf);
        asm volatile("s_waitcnt lgkmcnt(0)" ::: "memory");
        __builtin_amdgcn_s_barrier();
        __builtin_amdgcn_sched_barrier(0);
        __builtin_amdgcn_s_setprio(1);
#pragma unroll
        for (int m = 0; m < 4; ++m)
#pragma unroll
            for (int n = 0; n < 2; ++n) {
                acc[m + 4][n] = __builtin_amdgcn_mfma_f32_16x16x32_bf16(
                    af[m][0], bfA[n][0], acc[m + 4][n], 0, 0, 0);
                acc[m + 4][n] = __builtin_amdgcn_mfma_f32_16x16x32_bf16(
                    af[m][1], bfA[n][1], acc[m + 4][n], 0, 0, 0);
            }
        __builtin_amdgcn_s_setprio(0);

        // ---- phase 4 ----
        STG_HA0(tk + 2, buf);
        STG_HA1(tk + 2, buf);
        asm volatile("s_waitcnt vmcnt(6)" ::: "memory");
        __builtin_amdgcn_s_barrier();
        __builtin_amdgcn_sched_barrier(0);
        __builtin_amdgcn_s_setprio(1);
#pragma unroll
        for (int m = 0; m < 4; ++m)
#pragma unroll
            for (int n = 0; n < 2; ++n) {
                acc[m + 4][n + 2] = __builtin_amdgcn_mfma_f32_16x16x32_bf16(
                    af[m][0], bfB[n][0], acc[m + 4][n + 2], 0, 0, 0);
                acc[m + 4][n + 2] = __builtin_amdgcn_mfma_f32_16x16x32_bf16(
                    af[m][1], bfB[n][1], acc[m + 4][n + 2], 0, 0, 0);
            }
        __builtin_amdgcn_s_setprio(0);
    }
#undef STG_HA0
#undef STG_HA1
#undef STG_HB0
#undef STG_HB1

    const int crow = (lane >> 4) << 2;
#pragma unroll
    for (int m = 0; m < 8; ++m) {
        int rbase = row0 + wr * 128 + m * 16 + crow;
#pragma unroll
        for (int r = 0; r < 4; ++r) {
            int row = rbase + r;
            if (row < M) {
                unsigned short* Yp = Y + (size_t)row * 1024 + col0 + wc * 64 + fr16;
#pragma unroll
                for (int n = 0; n < 4; ++n)
                    Yp[n * 16] = f2bf(acc[m][n][r]);
            }
        }
    }
}

// ---------------- agg1: mean-gather(Yl) + b1' + self(Yr) + ReLU -> h (bf16) ------
__global__ __launch_bounds__(256) void agg1_kernel(
    const unsigned short* __restrict__ Y, unsigned short* __restrict__ Hh,
    const int* __restrict__ row_start, const int* __restrict__ colidx,
    const float* __restrict__ b1p, int n)
{
    int wid  = (blockIdx.x * blockDim.x + threadIdx.x) >> 6;
    int lane = threadIdx.x & 63;
    if (wid >= n) return;
    int c0 = lane * 8;
    float bb[8];
    *(float4*)&bb[0] = *(const float4*)&b1p[c0];
    *(float4*)&bb[4] = *(const float4*)&b1p[c0 + 4];

    int s0 = row_start[wid], s1 = row_start[wid + 1];
    float acc[8] = {0, 0, 0, 0, 0, 0, 0, 0};
    int i = s0;
    for (; i + 4 <= s1; i += 4) {
        int src0 = colidx[i], src1 = colidx[i + 1];
        int src2 = colidx[i + 2], src3 = colidx[i + 3];
        u16x8 v0 = *(const u16x8*)&Y[(size_t)src0 * 1024 + c0];
        u16x8 v1 = *(const u16x8*)&Y[(size_t)src1 * 1024 + c0];
        u16x8 v2 = *(const u16x8*)&Y[(size_t)src2 * 1024 + c0];
        u16x8 v3 = *(const u16x8*)&Y[(size_t)src3 * 1024 + c0];
#pragma unroll
        for (int j = 0; j < 8; ++j)
            acc[j] += (bf2f(v0[j]) + bf2f(v1[j])) + (bf2f(v2[j]) + bf2f(v3[j]));
    }
    for (; i < s1; ++i) {
        int src = colidx[i];
        u16x8 v = *(const u16x8*)&Y[(size_t)src * 1024 + c0];
#pragma unroll
        for (int j = 0; j < 8; ++j) acc[j] += bf2f(v[j]);
    }
    float inv = 1.0f / fmaxf((float)(s1 - s0), 1.0f);
    u16x8 sv = *(const u16x8*)&Y[(size_t)wid * 1024 + 512 + c0];
    unsigned short o[8];
#pragma unroll
    for (int j = 0; j < 8; ++j) {
        float pre = acc[j] * inv + bb[j] + bf2f(sv[j]);
        o[j] = f2bf(fmaxf(pre, 0.0f));
    }
    *(u16x8*)&Hh[(size_t)wid * 512 + c0] = *(u16x8*)o;
}

// ---------------- GEMM2: U[M x 128](bf16) = h[M x 512](bf16) @ BT2^T ------------
__global__ __launch_bounds__(256) void gemm2_bf16(
    const unsigned short* __restrict__ Hh, int M,
    const unsigned short* __restrict__ BT2,
    unsigned short* __restrict__ U)
{
    __shared__ __align__(16) unsigned short As2[2][128][32];
    __shared__ __align__(16) unsigned short Bs2[2][128][32];

    const int t    = threadIdx.x;
    const int wid  = t >> 6;
    const int lane = t & 63;
    const int row0 = blockIdx.x << 7;

    const int c_lo = wid * 64 + lane;
    const int c_hi = c_lo + 256;
    const int s_lo = ((c_lo & 3) ^ ((c_lo >> 3) & 3)) << 3;
    const int s_hi = ((c_hi & 3) ^ ((c_hi >> 3) & 3)) << 3;
    int ra = row0 + (c_lo >> 2); if (ra >= M) ra = M - 1;
    int rbw = row0 + (c_hi >> 2); if (rbw >= M) rbw = M - 1;
    const unsigned short* aSrc0 = Hh + (size_t)ra * 512 + s_lo;
    const unsigned short* aSrc1 = Hh + (size_t)rbw * 512 + s_hi;
    const unsigned short* bSrc0 = BT2 + (size_t)(c_lo >> 2) * 512 + s_lo;
    const unsigned short* bSrc1 = BT2 + (size_t)(c_hi >> 2) * 512 + s_hi;

    const int wr   = wid >> 1, wc = wid & 1;
    const int fr16 = lane & 15;
    const int gsw2 = ((lane >> 4) ^ ((fr16 >> 1) & 3)) << 4;

    f32x4 acc[4][4];
#pragma unroll
    for (int m = 0; m < 4; ++m)
#pragma unroll
        for (int n = 0; n < 4; ++n) acc[m][n] = (f32x4)0.0f;

#define STAGE2(kt, buf) do {                                                  \
        int ko = (kt) * 32;                                                   \
        GLL16(aSrc0 + ko, (unsigned short*)&As2[buf][0][0] + (size_t)c_lo * 8);  \
        GLL16(aSrc1 + ko, (unsigned short*)&As2[buf][0][0] + (size_t)c_hi * 8);  \
        GLL16(bSrc0 + ko, (unsigned short*)&Bs2[buf][0][0] + (size_t)c_lo * 8);  \
        GLL16(bSrc1 + ko, (unsigned short*)&Bs2[buf][0][0] + (size_t)c_hi * 8);  \
    } while (0)

    STAGE2(0, 0);
    int cur = 0;
    for (int it = 0; it < NT2; ++it) {
        __syncthreads();
        if (it + 1 < NT2) STAGE2(it + 1, cur ^ 1);

        const char* Ab = (const char*)&As2[cur][0][0];
        const char* Bb = (const char*)&Bs2[cur][0][0];
        bf16x8 af[4], bfr[4];
#pragma unroll
        for (int m = 0; m < 4; ++m)
            af[m] = *(const bf16x8*)(Ab + ((wr * 64 + m * 16 + fr16) << 6) + gsw2);
#pragma unroll
        for (int n = 0; n < 4; ++n)
            bfr[n] = *(const bf16x8*)(Bb + ((wc * 64 + n * 16 + fr16) << 6) + gsw2);
#pragma unroll
        for (int m = 0; m < 4; ++m)
#pragma unroll
            for (int n = 0; n < 4; ++n)
                acc[m][n] = __builtin_amdgcn_mfma_f32_16x16x32_bf16(
                    af[m], bfr[n], acc[m][n], 0, 0, 0);
        cur ^= 1;
    }
#undef STAGE2

    const int crow = (lane >> 4) << 2;
#pragma unroll
    for (int m = 0; m < 4; ++m) {
        int rbase = row0 + wr * 64 + m * 16 + crow;
#pragma unroll
        for (int r = 0; r < 4; ++r) {
            int row = rbase + r;
            if (row < M) {
                unsigned short* Up = U + (size_t)row * 128 + wc * 64 + fr16;
#pragma unroll
                for (int n = 0; n < 4; ++n)
                    Up[n * 16] = f2bf(acc[m][n][r]);
            }
        }
    }
}

// ---------------- agg2: mean-gather(Ul) + b2 + self(Ur) -> out (f32) ----------------
__global__ __launch_bounds__(256) void agg2_kernel(
    const unsigned short* __restrict__ U,
    const int* __restrict__ row_start, const int* __restrict__ colidx,
    const float* __restrict__ b2, float* __restrict__ out, int n)
{
    int wid  = (blockIdx.x * blockDim.x + threadIdx.x) >> 6;
    int lane = threadIdx.x & 63;
    if (wid >= n) return;
    int s0 = row_start[wid], s1 = row_start[wid + 1];
    float acc = 0.f;
    int i = s0;
    for (; i + 4 <= s1; i += 4) {
        int src0 = colidx[i], src1 = colidx[i + 1];
        int src2 = colidx[i + 2], src3 = colidx[i + 3];
        acc += (bf2f(U[(size_t)src0 * 128 + lane]) + bf2f(U[(size_t)src1 * 128 + lane]))
             + (bf2f(U[(size_t)src2 * 128 + lane]) + bf2f(U[(size_t)src3 * 128 + lane]));
    }
    for (; i < s1; ++i) acc += bf2f(U[(size_t)colidx[i] * 128 + lane]);
    float inv = 1.0f / fmaxf((float)(s1 - s0), 1.0f);
    float z = acc * inv + b2[lane] + bf2f(U[(size_t)wid * 128 + 64 + lane]);
    out[(size_t)wid * 64 + lane] = z;
}

extern "C" void kernel_launch(void* const* d_in, const int* in_sizes, int n_in,
                              void* d_out, int out_size, void* d_ws, size_t ws_size,
                              hipStream_t stream) {
    const float* x     = (const float*)d_in[0];
    const int*   ei    = (const int*)d_in[1];
    const float* W1l   = (const float*)d_in[2];
    const float* b1    = (const float*)d_in[3];
    const float* W1r   = (const float*)d_in[4];
    const float* gamma = (const float*)d_in[5];
    const float* beta  = (const float*)d_in[6];
    const float* mean  = (const float*)d_in[7];
    const float* var   = (const float*)d_in[8];
    const float* W2l   = (const float*)d_in[9];
    const float* b2    = (const float*)d_in[10];
    const float* W2r   = (const float*)d_in[11];
    float* out = (float*)d_out;

    const int N = in_sizes[0] / 2000;   // 50000
    const int E = in_sizes[1] / 2;      // 800000
    const int nby = (N + 127) / 128;

    // Workspace (proven 315 MB aliasing layout):
    //   xb | Y | BT | BT2 | b1p | cnt | row_start | colidx
    //   Hh aliases xb (dead after gemm1); U aliases Y (dead after agg1)
    char* ws = (char*)d_ws;
    unsigned short* xb  = (unsigned short*)ws;
    unsigned short* Y   = xb + (size_t)N * KP;
    unsigned short* BT  = Y + (size_t)N * 1024;
    unsigned short* BT2 = BT + (size_t)1024 * KP;
    float* b1p     = (float*)(BT2 + (size_t)128 * 512);
    int* cnt       = (int*)(b1p + 512);
    int* row_start = cnt + N;
    int* colidx    = row_start + N + 4;
    unsigned short* Hh = xb;   // alias: xb dead after gemm1
    unsigned short* U  = Y;    // alias: Y dead after agg1

    hipMemsetAsync(cnt, 0, (size_t)N * sizeof(int), stream);

    prep2<<<4129, 256, 0, stream>>>(
        x, xb, N, W1l, W1r, gamma, beta, mean, var, b1, BT,
        W2l, W2r, BT2, b1p, ei, cnt, E);

    scan_kernel<<<1, 1024, 0, stream>>>(cnt, row_start, N);

    int nbr = (N + 255) / 256;
    int nwg = nbr * 4;
    int fillb = (E + 511) / 512;
    gemm1_256<<<nwg + fillb, 512, 0, stream>>>(
        xb, N, BT, Y, ei, E, row_start, cnt, colidx);

    agg1_kernel<<<(N + 3) / 4, 256, 0, stream>>>(
        Y, Hh, row_start, colidx, b1p, N);
    gemm2_bf16<<<nby, 256, 0, stream>>>(Hh, N, BT2, U);
    agg2_kernel<<<(N + 3) / 4, 256, 0, stream>>>(
        U, row_start, colidx, b2, out, N);
}